// Round 4
// baseline (1004.388 us; speedup 1.0000x reference)
//
#include <hip/hip_runtime.h>

// Drifter: B=1048576 trajectories, T=101 (t = 0,20,...,2000), FS_ORDER=8.
// x_{n+1} = x_n + (sum_f sin(f x)sw[f] + cos(f x)cw[f]) * 20
// Outputs (concatenated): t_mesh [B,101], xt [B,101] (wrapped to (-pi,pi]).
// t_sample is unused by the reference outputs.
//
// V4: SPLIT into two kernels.
//   kernel 1 (tmesh): pure fully-coalesced nontemporal float4 stream --
//     structurally identical to the harness fill that hits 6.27 TB/s.
//     423 MB -> ~70 us.
//   kernel 2 (xt): ODE compute + wave-private LDS transpose + coalesced
//     dwordx4 writes. No barriers (V3). Store queue no longer shared with
//     the t_mesh burst -> compute issue is not throttled by NT backpressure.
//   Arithmetic bit-identical to V1-V3 (absmax preserved).

#define B_TOTAL   1048576
#define T_STEPS   101
#define FS        8
#define DT_F      20.0f
#define CHUNK     32
#define LDSTR     (CHUNK + 1)   // stride 33 == 1 mod 32 -> conflict-free
#define PI_F      3.14159265358979323846f
#define TWO_PI_F  6.28318530717958647692f
#define INV_2PI_F 0.15915494309189533577f

typedef float f4 __attribute__((ext_vector_type(4)));

// ---------------------------------------------------------------------------
// Kernel 1: t_mesh writer. Each block owns a contiguous 25856-float region
// (256 rows x 101 cols); 25 full float4 waves + 64-thread tail.
// ---------------------------------------------------------------------------
__global__ __launch_bounds__(256) void tmesh_kernel(float* __restrict__ out_tmesh)
{
    const int tid = threadIdx.x;
    f4* tm = (f4*)(out_tmesh + (size_t)blockIdx.x * (256 * T_STEPS));

    int col = (tid * 4) % T_STEPS;              // compile-time magic div
#pragma unroll
    for (int it = 0; it < 25; ++it) {
        int c0 = col;
        int c1 = c0 + 1; if (c1 >= T_STEPS) c1 -= T_STEPS;
        int c2 = c1 + 1; if (c2 >= T_STEPS) c2 -= T_STEPS;
        int c3 = c2 + 1; if (c3 >= T_STEPS) c3 -= T_STEPS;
        f4 v = { DT_F * (float)c0, DT_F * (float)c1,
                 DT_F * (float)c2, DT_F * (float)c3 };
        __builtin_nontemporal_store(v, tm + it * 256 + tid);
        col += 14;                               // 1024 % 101 == 14
        if (col >= T_STEPS) col -= T_STEPS;
    }
    if (tid < 64) {                              // tail: floats [25600, 25856)
        const int base = 25600 + tid * 4;
        int c0 = base % T_STEPS;
        int c1 = c0 + 1; if (c1 >= T_STEPS) c1 -= T_STEPS;
        int c2 = c1 + 1; if (c2 >= T_STEPS) c2 -= T_STEPS;
        int c3 = c2 + 1; if (c3 >= T_STEPS) c3 -= T_STEPS;
        f4 v = { DT_F * (float)c0, DT_F * (float)c1,
                 DT_F * (float)c2, DT_F * (float)c3 };
        __builtin_nontemporal_store(v, tm + 6400 + tid);
    }
}

// ---------------------------------------------------------------------------
// Kernel 2: ODE + wave-private transpose + xt writes. Barrier-free (V3).
// ---------------------------------------------------------------------------
__global__ __launch_bounds__(256) void xt_kernel(
    const float* __restrict__ x0,
    const float* __restrict__ sw,
    const float* __restrict__ cw,
    float* __restrict__ out_xt)
{
    __shared__ float lds[256 * LDSTR];

    const int tid = threadIdx.x;
    const int b   = blockIdx.x * 256 + tid;

    float x = x0[b];

    // weights: wave-uniform constant-index loads -> scalar loads, once
    float swr[FS], cwr[FS];
#pragma unroll
    for (int f = 0; f < FS; ++f) { swr[f] = sw[f]; cwr[f] = cw[f]; }

    // wave-private transpose geometry: wave w owns rows [64w, 64w+64)
    const int lane  = tid & 63;
    const int wbase = tid & ~63;      // 64 * wave_id (WG-relative row base)
    const int q     = lane & 7;       // 4-col group within the 32-col chunk
    const int rl    = lane >> 3;      // 0..7
    float* xtb = out_xt + (size_t)blockIdx.x * (256 * T_STEPS);

#pragma unroll
    for (int chunk = 0; chunk < 4; ++chunk) {
        const int cbase = chunk * CHUNK;
        const int csize = (T_STEPS - cbase) < CHUNK ? (T_STEPS - cbase) : CHUNK;

        // ---- compute csize trajectory values into this wave's LDS slab ----
        for (int c = 0; c < csize; ++c) {
            // wrapped x at global time index j = cbase + c
            float v = x + PI_F;
            // JAX/numpy mod semantics: result in [0, 2pi)
            float w = v - floorf(v * INV_2PI_F) * TWO_PI_F - PI_F;
            lds[tid * LDSTR + c] = w;           // bank (tid + c) % 32: 2-way, free

            if (cbase + c < T_STEPS - 1) {      // 100 Euler steps total
                float s1 = __sinf(x);
                float c1 = __cosf(x);
                float tc = 2.0f * c1;
                // f=0: sin term 0, cos term cw[0]
                float acc  = cwr[0] + s1 * swr[1] + c1 * cwr[1];
                float skm1 = 0.0f, ckm1 = 1.0f; // k=0
                float sk = s1, ck = c1;         // k=1
#pragma unroll
                for (int f = 2; f < FS; ++f) {  // Chebyshev recurrence
                    float sn = tc * sk - skm1;
                    float cn = tc * ck - ckm1;
                    skm1 = sk; ckm1 = ck;
                    sk = sn;   ck = cn;
                    acc += sn * swr[f] + cn * cwr[f];
                }
                x += acc * DT_F;
            }
        }

        // compiler fence only: in-order per-wave DS processing gives
        // cross-lane visibility within the wave; no hardware barrier.
        asm volatile("" ::: "memory");

        // ---- wave-private transpose writeback ----
        // lane -> rows (wbase + rl + 8i), cols cbase + 4q .. +3.
        // Global: 8 x 128B segments per wave instruction.
        if (chunk < 3) {
#pragma unroll
            for (int i = 0; i < 8; ++i) {
                const int r = wbase + rl + (i << 3);
                const float* lp = &lds[r * LDSTR + (q << 2)];
                const float v0 = lp[0], v1 = lp[1], v2 = lp[2], v3 = lp[3];
                float* p = xtb + (size_t)r * T_STEPS + (cbase + (q << 2));
                p[0] = v0; p[1] = v1; p[2] = v2; p[3] = v3;
            }
        } else {
            // tail chunk: cols 96..100 (csize = 5)
#pragma unroll
            for (int i = 0; i < 8; ++i) {
                const int r = wbase + rl + (i << 3);
                const float* lp = &lds[r * LDSTR];
                float* p = xtb + (size_t)r * T_STEPS + 96;
                if (q == 0) {
                    const float v0 = lp[0], v1 = lp[1], v2 = lp[2], v3 = lp[3];
                    p[0] = v0; p[1] = v1; p[2] = v2; p[3] = v3;
                } else if (q == 1) {
                    p[4] = lp[4];
                }
            }
        }

        // fence before next chunk's compute overwrites the slab (WAR across lanes)
        asm volatile("" ::: "memory");
    }
}

extern "C" void kernel_launch(void* const* d_in, const int* in_sizes, int n_in,
                              void* d_out, int out_size, void* d_ws, size_t ws_size,
                              hipStream_t stream) {
    const float* x0 = (const float*)d_in[0];   // [B] fp32
    const float* sw = (const float*)d_in[1];   // [8] fp32
    const float* cw = (const float*)d_in[2];   // [8] fp32
    // d_in[3] = t_sample (int32) -- unused by reference outputs

    float* out = (float*)d_out;
    const long long half = (long long)B_TOTAL * T_STEPS;  // t_mesh first, xt second

    tmesh_kernel<<<B_TOTAL / 256, 256, 0, stream>>>(out);
    xt_kernel<<<B_TOTAL / 256, 256, 0, stream>>>(x0, sw, cw, out + half);
}

// Round 5
// 991.638 us; speedup vs baseline: 1.0129x; 1.0129x over previous
//
#include <hip/hip_runtime.h>

// Drifter: B=1048576 trajectories, T=101 (t = 0,20,...,2000), FS_ORDER=8.
// x_{n+1} = x_n + (sum_f sin(f x)sw[f] + cos(f x)cw[f]) * 20
// Outputs (concatenated): t_mesh [B,101], xt [B,101] (wrapped to (-pi,pi]).
// t_sample is unused by the reference outputs.
//
// V5: ROLLED LOOPS (I-cache theory). Previous versions fully unrolled the
//     100-step Euler chain (~40 KB straight-line code) -> L1I (32 KB) thrash,
//     worsened by barrier-free waves drifting into different code regions.
//     All loops now #pragma unroll 1 => ~2 KB code footprint.
//     Also: chunks {32,32,37} (tail merged, LDS stride 39, 4 blocks/CU) to
//     halve partial-line write episodes on the 404 B xt rows.
//     Single kernel (V4 split regressed), barrier-free (V3), NT t_mesh burst.
//     Arithmetic bit-identical to V1-V4 (absmax preserved).

#define B_TOTAL   1048576
#define T_STEPS   101
#define FS        8
#define DT_F      20.0f
#define LDSTR     39            // max chunk 37 + pad; 39 mod 32 = 7 (odd) -> <=4-way banks
#define PI_F      3.14159265358979323846f
#define TWO_PI_F  6.28318530717958647692f
#define INV_2PI_F 0.15915494309189533577f

typedef float f4 __attribute__((ext_vector_type(4)));

__global__ __launch_bounds__(256) void drifter_kernel(
    const float* __restrict__ x0,
    const float* __restrict__ sw,
    const float* __restrict__ cw,
    float* __restrict__ out_tmesh,
    float* __restrict__ out_xt)
{
    __shared__ float lds[256 * LDSTR];   // 39,936 B -> 4 blocks/CU

    const int tid = threadIdx.x;
    const int b   = blockIdx.x * 256 + tid;
    const size_t rowbase = (size_t)blockIdx.x * (256 * T_STEPS);

    // issue the x0 load first; latency hides under the t_mesh burst
    float x = x0[b];

    // weights: wave-uniform constant-index loads -> scalar loads, once
    float swr[FS], cwr[FS];
#pragma unroll
    for (int f = 0; f < FS; ++f) { swr[f] = sw[f]; cwr[f] = cw[f]; }

    // ---- t_mesh: fully-coalesced nontemporal float4 burst (rolled) ----
    // 6464 float4 per block region (16B-aligned); fire-and-forget, drains
    // under the ODE compute phase.
    {
        f4* tm = (f4*)(out_tmesh + rowbase);
        int col = (tid * 4) % T_STEPS;
#pragma unroll 1
        for (int it = 0; it < 25; ++it) {
            int c0 = col;
            int c1 = c0 + 1; if (c1 >= T_STEPS) c1 -= T_STEPS;
            int c2 = c1 + 1; if (c2 >= T_STEPS) c2 -= T_STEPS;
            int c3 = c2 + 1; if (c3 >= T_STEPS) c3 -= T_STEPS;
            f4 v = { DT_F * (float)c0, DT_F * (float)c1,
                     DT_F * (float)c2, DT_F * (float)c3 };
            __builtin_nontemporal_store(v, tm + it * 256 + tid);
            col += 14;                           // 1024 % 101 == 14
            if (col >= T_STEPS) col -= T_STEPS;
        }
        if (tid < 64) {                          // tail: floats [25600, 25856)
            const int base = 25600 + tid * 4;
            int c0 = base % T_STEPS;
            int c1 = c0 + 1; if (c1 >= T_STEPS) c1 -= T_STEPS;
            int c2 = c1 + 1; if (c2 >= T_STEPS) c2 -= T_STEPS;
            int c3 = c2 + 1; if (c3 >= T_STEPS) c3 -= T_STEPS;
            f4 v = { DT_F * (float)c0, DT_F * (float)c1,
                     DT_F * (float)c2, DT_F * (float)c3 };
            __builtin_nontemporal_store(v, tm + 6400 + tid);
        }
    }

    // wave-private transpose geometry: wave w owns rows [64w, 64w+64)
    const int lane  = tid & 63;
    const int wbase = tid & ~63;      // 64 * wave_id (WG-relative row base)
    const int q     = lane & 7;       // 4-col group
    const int rl    = lane >> 3;      // 0..7
    float* xtb = out_xt + rowbase;

    float* myrow = &lds[tid * LDSTR];

    // ================= chunk 0: cols 0..31 (always step) =================
#pragma unroll 1
    for (int c = 0; c < 32; ++c) {
        float v = x + PI_F;
        float w = v - floorf(v * INV_2PI_F) * TWO_PI_F - PI_F;
        myrow[c] = w;
        // Euler step (cols 0..31 are all < 100)
        float s1 = __sinf(x), c1 = __cosf(x);
        float tc = 2.0f * c1;
        float acc  = cwr[0] + s1 * swr[1] + c1 * cwr[1];
        float skm1 = 0.0f, ckm1 = 1.0f;
        float sk = s1, ck = c1;
#pragma unroll
        for (int f = 2; f < FS; ++f) {
            float sn = tc * sk - skm1;
            float cn = tc * ck - ckm1;
            skm1 = sk; ckm1 = ck;
            sk = sn;   ck = cn;
            acc += sn * swr[f] + cn * cwr[f];
        }
        x += acc * DT_F;
    }
    asm volatile("" ::: "memory");
#pragma unroll 1
    for (int i = 0; i < 8; ++i) {
        const int r = wbase + rl + (i << 3);
        const float* lp = &lds[r * LDSTR + (q << 2)];
        const float v0 = lp[0], v1 = lp[1], v2 = lp[2], v3 = lp[3];
        float* p = xtb + (size_t)r * T_STEPS + (q << 2);
        p[0] = v0; p[1] = v1; p[2] = v2; p[3] = v3;
    }
    asm volatile("" ::: "memory");

    // ================= chunk 1: cols 32..63 (always step) ================
#pragma unroll 1
    for (int c = 0; c < 32; ++c) {
        float v = x + PI_F;
        float w = v - floorf(v * INV_2PI_F) * TWO_PI_F - PI_F;
        myrow[c] = w;
        float s1 = __sinf(x), c1 = __cosf(x);
        float tc = 2.0f * c1;
        float acc  = cwr[0] + s1 * swr[1] + c1 * cwr[1];
        float skm1 = 0.0f, ckm1 = 1.0f;
        float sk = s1, ck = c1;
#pragma unroll
        for (int f = 2; f < FS; ++f) {
            float sn = tc * sk - skm1;
            float cn = tc * ck - ckm1;
            skm1 = sk; ckm1 = ck;
            sk = sn;   ck = cn;
            acc += sn * swr[f] + cn * cwr[f];
        }
        x += acc * DT_F;
    }
    asm volatile("" ::: "memory");
#pragma unroll 1
    for (int i = 0; i < 8; ++i) {
        const int r = wbase + rl + (i << 3);
        const float* lp = &lds[r * LDSTR + (q << 2)];
        const float v0 = lp[0], v1 = lp[1], v2 = lp[2], v3 = lp[3];
        float* p = xtb + (size_t)r * T_STEPS + 32 + (q << 2);
        p[0] = v0; p[1] = v1; p[2] = v2; p[3] = v3;
    }
    asm volatile("" ::: "memory");

    // ============== chunk 2: cols 64..100 (step while col < 100) =========
#pragma unroll 1
    for (int c = 0; c < 37; ++c) {
        float v = x + PI_F;
        float w = v - floorf(v * INV_2PI_F) * TWO_PI_F - PI_F;
        myrow[c] = w;
        if (c < 36) {                 // last stored col (100) gets no step
            float s1 = __sinf(x), c1 = __cosf(x);
            float tc = 2.0f * c1;
            float acc  = cwr[0] + s1 * swr[1] + c1 * cwr[1];
            float skm1 = 0.0f, ckm1 = 1.0f;
            float sk = s1, ck = c1;
#pragma unroll
            for (int f = 2; f < FS; ++f) {
                float sn = tc * sk - skm1;
                float cn = tc * ck - ckm1;
                skm1 = sk; ckm1 = ck;
                sk = sn;   ck = cn;
                acc += sn * swr[f] + cn * cwr[f];
            }
            x += acc * DT_F;
        }
    }
    asm volatile("" ::: "memory");
#pragma unroll 1
    for (int i = 0; i < 8; ++i) {
        const int r = wbase + rl + (i << 3);
        const float* lp = &lds[r * LDSTR];
        float* p = xtb + (size_t)r * T_STEPS;
        // cols 64..95 from LDS cols 0..31
        {
            const float v0 = lp[(q << 2) + 0], v1 = lp[(q << 2) + 1];
            const float v2 = lp[(q << 2) + 2], v3 = lp[(q << 2) + 3];
            p[64 + (q << 2) + 0] = v0; p[64 + (q << 2) + 1] = v1;
            p[64 + (q << 2) + 2] = v2; p[64 + (q << 2) + 3] = v3;
        }
        // tail cols 96..100 from LDS cols 32..36
        if (q == 0) {
            const float v0 = lp[32], v1 = lp[33], v2 = lp[34], v3 = lp[35];
            p[96] = v0; p[97] = v1; p[98] = v2; p[99] = v3;
        } else if (q == 1) {
            p[100] = lp[36];
        }
    }
}

extern "C" void kernel_launch(void* const* d_in, const int* in_sizes, int n_in,
                              void* d_out, int out_size, void* d_ws, size_t ws_size,
                              hipStream_t stream) {
    const float* x0 = (const float*)d_in[0];   // [B] fp32
    const float* sw = (const float*)d_in[1];   // [8] fp32
    const float* cw = (const float*)d_in[2];   // [8] fp32
    // d_in[3] = t_sample (int32) -- unused by reference outputs

    float* out = (float*)d_out;
    const long long half = (long long)B_TOTAL * T_STEPS;  // t_mesh first, xt second

    drifter_kernel<<<B_TOTAL / 256, 256, 0, stream>>>(x0, sw, cw, out, out + half);
}

// Round 6
// 868.104 us; speedup vs baseline: 1.1570x; 1.1423x over previous
//
#include <hip/hip_runtime.h>

// Drifter: B=1048576 trajectories, T=101 (t = 0,20,...,2000), FS_ORDER=8.
// x_{n+1} = x_n + (sum_f sin(f x)sw[f] + cos(f x)cw[f]) * 20
// Outputs (concatenated): t_mesh [B,101], xt [B,101] (wrapped to (-pi,pi]).
// t_sample is unused by the reference outputs.
//
// V6: FULL-LINE SINGLE-PASS STORES (write-allocate theory).
//   Previous xt writebacks stored unaligned 128B segments, and each row's
//   cache lines were written in 3 temporal episodes -> partial-dirty L2
//   evictions + write-allocate fetches from HBM -> ~1.1 TB/s effective.
//   Now: 128-thread blocks; the block's whole xt region (128 rows x 101
//   cols = 51,712 B, exactly 404 x 128B lines, 128B-aligned) is computed
//   into LDS first, then streamed out as a contiguous nontemporal float4
//   burst -- structurally identical to the 6.27 TB/s fillBuffer.
//   Wave-private halves (rows 0-63 / 64-127) -> still ZERO barriers.
//   Arithmetic bit-identical to V1-V5 (absmax preserved).

#define B_TOTAL   1048576
#define T_STEPS   101
#define FS        8
#define DT_F      20.0f
#define PI_F      3.14159265358979323846f
#define TWO_PI_F  6.28318530717958647692f
#define INV_2PI_F 0.15915494309189533577f

typedef float f4 __attribute__((ext_vector_type(4)));

__global__ __launch_bounds__(128) void drifter_kernel(
    const float* __restrict__ x0,
    const float* __restrict__ sw,
    const float* __restrict__ cw,
    float* __restrict__ out_tmesh,
    float* __restrict__ out_xt)
{
    // 128 rows x 101 cols, flat row-major, 51,712 B (16B-aligned via f4).
    // LDS-bound occupancy: 3 blocks/CU = 6 waves/CU (fill hits 78% peak BW
    // at 10.4% occupancy, and compute is ~50us of issue -> enough).
    __shared__ f4 lds4[3232];
    float* lds = (float*)lds4;

    const int tid = threadIdx.x;
    const int b   = blockIdx.x * 128 + tid;
    const size_t blkbase = (size_t)blockIdx.x * (128 * T_STEPS);  // floats; 51712B => 128B-aligned

    // issue the x0 load first; latency hides under the t_mesh burst
    float x = x0[b];

    // weights: wave-uniform constant-index loads -> scalar loads, once
    float swr[FS], cwr[FS];
#pragma unroll
    for (int f = 0; f < FS; ++f) { swr[f] = sw[f]; cwr[f] = cw[f]; }

    // ---- t_mesh: contiguous aligned nontemporal f4 burst (3232 f4/block) ----
    // Fire-and-forget; drains under the ODE compute phase (no barriers ever).
    {
        f4* tm = (f4*)(out_tmesh + blkbase);
        int col = (tid * 4) % T_STEPS;
#pragma unroll 1
        for (int it = 0; it < 25; ++it) {
            int c0 = col;
            int c1 = c0 + 1; if (c1 >= T_STEPS) c1 -= T_STEPS;
            int c2 = c1 + 1; if (c2 >= T_STEPS) c2 -= T_STEPS;
            int c3 = c2 + 1; if (c3 >= T_STEPS) c3 -= T_STEPS;
            f4 v = { DT_F * (float)c0, DT_F * (float)c1,
                     DT_F * (float)c2, DT_F * (float)c3 };
            __builtin_nontemporal_store(v, tm + it * 128 + tid);
            col += 7;                            // (128*4) % 101 == 7
            if (col >= T_STEPS) col -= T_STEPS;
        }
        if (tid < 32) {                          // tail: f4 [3200, 3232)
            const int base = 12800 + tid * 4;
            int c0 = base % T_STEPS;             // 12800 % 101 = 74
            int c1 = c0 + 1; if (c1 >= T_STEPS) c1 -= T_STEPS;
            int c2 = c1 + 1; if (c2 >= T_STEPS) c2 -= T_STEPS;
            int c3 = c2 + 1; if (c3 >= T_STEPS) c3 -= T_STEPS;
            f4 v = { DT_F * (float)c0, DT_F * (float)c1,
                     DT_F * (float)c2, DT_F * (float)c3 };
            __builtin_nontemporal_store(v, tm + 3200 + tid);
        }
    }

    // ---- compute the FULL trajectory (101 values) into LDS row tid ----
    // Bank pattern for myrow[c]: (101*tid + c) % 32 = (5*tid + c) % 32,
    // gcd(5,32)=1 -> 64 lanes cover 32 banks x2 -> conflict-free.
    {
        float* myrow = lds + tid * T_STEPS;
#pragma unroll 1
        for (int c = 0; c < T_STEPS; ++c) {
            float v = x + PI_F;
            // JAX/numpy mod semantics: result in [0, 2pi)
            float w = v - floorf(v * INV_2PI_F) * TWO_PI_F - PI_F;
            myrow[c] = w;

            if (c < T_STEPS - 1) {               // 100 Euler steps total
                float s1 = __sinf(x);
                float c1 = __cosf(x);
                float tc = 2.0f * c1;
                // f=0: sin term 0, cos term cw[0]
                float acc  = cwr[0] + s1 * swr[1] + c1 * cwr[1];
                float skm1 = 0.0f, ckm1 = 1.0f;  // k=0
                float sk = s1, ck = c1;          // k=1
#pragma unroll
                for (int f = 2; f < FS; ++f) {   // Chebyshev recurrence
                    float sn = tc * sk - skm1;
                    float cn = tc * ck - ckm1;
                    skm1 = sk; ckm1 = ck;
                    sk = sn;   ck = cn;
                    acc += sn * swr[f] + cn * cwr[f];
                }
                x += acc * DT_F;
            }
        }
    }

    // compiler fence only: writeback is wave-private (wave w reads exactly
    // the rows its own lanes wrote); in-order per-wave DS processing gives
    // cross-lane visibility without a hardware barrier.
    asm volatile("" ::: "memory");

    // ---- xt: contiguous aligned nontemporal f4 burst ----
    // Wave w owns f4 range [1616*w, 1616*(w+1)) = rows [64w, 64w+64) exactly
    // (64 rows x 101 floats = 6464 floats = 1616 f4). Single pass, full
    // lines, no L2 write-allocate -- structurally identical to the fill.
    {
        const int lane = tid & 63;
        const int wv   = tid >> 6;               // 0 or 1
        const f4* src  = lds4 + wv * 1616;
        f4* dst = (f4*)(out_xt + blkbase) + wv * 1616;
#pragma unroll 1
        for (int it = 0; it < 25; ++it) {
            f4 v = src[it * 64 + lane];
            __builtin_nontemporal_store(v, dst + it * 64 + lane);
        }
        if (lane < 16) {                         // tail: f4 [1600, 1616) of this wave
            f4 v = src[1600 + lane];
            __builtin_nontemporal_store(v, dst + 1600 + lane);
        }
    }
}

extern "C" void kernel_launch(void* const* d_in, const int* in_sizes, int n_in,
                              void* d_out, int out_size, void* d_ws, size_t ws_size,
                              hipStream_t stream) {
    const float* x0 = (const float*)d_in[0];   // [B] fp32
    const float* sw = (const float*)d_in[1];   // [8] fp32
    const float* cw = (const float*)d_in[2];   // [8] fp32
    // d_in[3] = t_sample (int32) -- unused by reference outputs

    float* out = (float*)d_out;
    const long long half = (long long)B_TOTAL * T_STEPS;  // t_mesh first, xt second

    drifter_kernel<<<B_TOTAL / 128, 128, 0, stream>>>(x0, sw, cw, out, out + half);
}

// Round 7
// 851.927 us; speedup vs baseline: 1.1790x; 1.0190x over previous
//
#include <hip/hip_runtime.h>

// Drifter: B=1048576 trajectories, T=101 (t = 0,20,...,2000), FS_ORDER=8.
// x_{n+1} = x_n + (sum_f sin(f x)sw[f] + cos(f x)cw[f]) * 20
// Outputs (concatenated): t_mesh [B,101], xt [B,101] (wrapped to (-pi,pi]).
// t_sample is unused by the reference outputs.
//
// V7: V6 structure, NORMAL stores (A/B vs nontemporal).
//   The 6.27 TB/s harness fill uses plain stores through L2 with ~zero
//   FETCH_SIZE -- full-line writes don't write-allocate-fetch; L2 writes
//   back full dirty lines at full HBM BW. V6's NT stores bypass L2 into
//   the write-combine path, the suspected ~3 TB/s limiter. Single changed
//   variable: store flavor. Geometry/arithmetic bit-identical to V6.

#define B_TOTAL   1048576
#define T_STEPS   101
#define FS        8
#define DT_F      20.0f
#define PI_F      3.14159265358979323846f
#define TWO_PI_F  6.28318530717958647692f
#define INV_2PI_F 0.15915494309189533577f

typedef float f4 __attribute__((ext_vector_type(4)));

__global__ __launch_bounds__(128) void drifter_kernel(
    const float* __restrict__ x0,
    const float* __restrict__ sw,
    const float* __restrict__ cw,
    float* __restrict__ out_tmesh,
    float* __restrict__ out_xt)
{
    // 128 rows x 101 cols, flat row-major, 51,712 B (16B-aligned via f4).
    // 3 blocks/CU (LDS-bound) = 6 waves/CU.
    __shared__ f4 lds4[3232];
    float* lds = (float*)lds4;

    const int tid = threadIdx.x;
    const int b   = blockIdx.x * 128 + tid;
    const size_t blkbase = (size_t)blockIdx.x * (128 * T_STEPS);  // floats; 51712B => 128B-aligned

    // issue the x0 load first; latency hides under the t_mesh burst
    float x = x0[b];

    // weights: wave-uniform constant-index loads -> scalar loads, once
    float swr[FS], cwr[FS];
#pragma unroll
    for (int f = 0; f < FS; ++f) { swr[f] = sw[f]; cwr[f] = cw[f]; }

    // ---- t_mesh: contiguous aligned f4 burst (3232 f4/block) ----
    // Fire-and-forget; drains under the ODE compute phase (no barriers ever).
    {
        f4* tm = (f4*)(out_tmesh + blkbase);
        int col = (tid * 4) % T_STEPS;
#pragma unroll 1
        for (int it = 0; it < 25; ++it) {
            int c0 = col;
            int c1 = c0 + 1; if (c1 >= T_STEPS) c1 -= T_STEPS;
            int c2 = c1 + 1; if (c2 >= T_STEPS) c2 -= T_STEPS;
            int c3 = c2 + 1; if (c3 >= T_STEPS) c3 -= T_STEPS;
            f4 v = { DT_F * (float)c0, DT_F * (float)c1,
                     DT_F * (float)c2, DT_F * (float)c3 };
            tm[it * 128 + tid] = v;
            col += 7;                            // (128*4) % 101 == 7
            if (col >= T_STEPS) col -= T_STEPS;
        }
        if (tid < 32) {                          // tail: f4 [3200, 3232)
            const int base = 12800 + tid * 4;
            int c0 = base % T_STEPS;             // 12800 % 101 = 74
            int c1 = c0 + 1; if (c1 >= T_STEPS) c1 -= T_STEPS;
            int c2 = c1 + 1; if (c2 >= T_STEPS) c2 -= T_STEPS;
            int c3 = c2 + 1; if (c3 >= T_STEPS) c3 -= T_STEPS;
            f4 v = { DT_F * (float)c0, DT_F * (float)c1,
                     DT_F * (float)c2, DT_F * (float)c3 };
            tm[3200 + tid] = v;
        }
    }

    // ---- compute the FULL trajectory (101 values) into LDS row tid ----
    // Bank pattern for myrow[c]: (101*tid + c) % 32 = (5*tid + c) % 32,
    // gcd(5,32)=1 -> 64 lanes cover 32 banks x2 -> conflict-free.
    {
        float* myrow = lds + tid * T_STEPS;
#pragma unroll 1
        for (int c = 0; c < T_STEPS; ++c) {
            float v = x + PI_F;
            // JAX/numpy mod semantics: result in [0, 2pi)
            float w = v - floorf(v * INV_2PI_F) * TWO_PI_F - PI_F;
            myrow[c] = w;

            if (c < T_STEPS - 1) {               // 100 Euler steps total
                float s1 = __sinf(x);
                float c1 = __cosf(x);
                float tc = 2.0f * c1;
                // f=0: sin term 0, cos term cw[0]
                float acc  = cwr[0] + s1 * swr[1] + c1 * cwr[1];
                float skm1 = 0.0f, ckm1 = 1.0f;  // k=0
                float sk = s1, ck = c1;          // k=1
#pragma unroll
                for (int f = 2; f < FS; ++f) {   // Chebyshev recurrence
                    float sn = tc * sk - skm1;
                    float cn = tc * ck - ckm1;
                    skm1 = sk; ckm1 = ck;
                    sk = sn;   ck = cn;
                    acc += sn * swr[f] + cn * cwr[f];
                }
                x += acc * DT_F;
            }
        }
    }

    // compiler fence only: writeback is wave-private (wave w reads exactly
    // the rows its own lanes wrote); in-order per-wave DS processing gives
    // cross-lane visibility without a hardware barrier.
    asm volatile("" ::: "memory");

    // ---- xt: contiguous aligned f4 burst ----
    // Wave w owns f4 range [1616*w, 1616*(w+1)) = rows [64w, 64w+64) exactly
    // (64 rows x 101 floats = 6464 floats = 1616 f4). Single pass, full
    // 128B lines through L2 -- structurally identical to the fill.
    {
        const int lane = tid & 63;
        const int wv   = tid >> 6;               // 0 or 1
        const f4* src  = lds4 + wv * 1616;
        f4* dst = (f4*)(out_xt + blkbase) + wv * 1616;
#pragma unroll 1
        for (int it = 0; it < 25; ++it) {
            dst[it * 64 + lane] = src[it * 64 + lane];
        }
        if (lane < 16) {                         // tail: f4 [1600, 1616) of this wave
            dst[1600 + lane] = src[1600 + lane];
        }
    }
}

extern "C" void kernel_launch(void* const* d_in, const int* in_sizes, int n_in,
                              void* d_out, int out_size, void* d_ws, size_t ws_size,
                              hipStream_t stream) {
    const float* x0 = (const float*)d_in[0];   // [B] fp32
    const float* sw = (const float*)d_in[1];   // [8] fp32
    const float* cw = (const float*)d_in[2];   // [8] fp32
    // d_in[3] = t_sample (int32) -- unused by reference outputs

    float* out = (float*)d_out;
    const long long half = (long long)B_TOTAL * T_STEPS;  // t_mesh first, xt second

    drifter_kernel<<<B_TOTAL / 128, 128, 0, stream>>>(x0, sw, cw, out, out + half);
}